// Round 9
// baseline (308.513 us; speedup 1.0000x reference)
//
#include <hip/hip_runtime.h>
#include <cstddef>

typedef _Float16 f16;
typedef __attribute__((ext_vector_type(4))) _Float16 f16x4;
typedef __attribute__((ext_vector_type(8))) _Float16 f16x8;
typedef __attribute__((ext_vector_type(4))) float f32x4;

namespace {
constexpr int kB = 16;
constexpr int kN = 2048;
constexpr int kD = 256;   // D_IN
constexpr int kC = 32;
constexpr int kH = 64;
constexpr int kHeads = 4;
constexpr int kKD = 64;
constexpr int kChunks = 32;                  // route n-chunks per b
constexpr int kRows = kN / kChunks;          // 64 rows per chunk
constexpr int kXJ = 64;                      // xpart sub-chunks (32 rows each)

// workspace offsets (floats)
constexpr size_t OFF_XPART = 0;                       // [B,64,D]         262144
constexpr size_t OFF_V     = OFF_XPART + 262144;      // [B,C,H]           32768
constexpr size_t OFF_WV    = OFF_V + 32768;           // [B,C,D] fp32     131072
constexpr size_t OFF_BV    = OFF_WV + 131072;         // [B,C]               512
constexpr size_t OFF_Y     = OFF_BV + 512;            // [B,C,D] (atomic) 131072
constexpr size_t OFF_CS    = OFF_Y + 131072;          // [B,C]               512
constexpr size_t OFF_XF16  = OFF_CS + 512;            // [B,N,D] f16     4194304
constexpr size_t OFF_WVH   = OFF_XF16 + 4194304;      // [B,C,D] f16       65536
constexpr size_t OFF_CSP   = OFF_WVH + 65536;         // [B,chunks,C]      16384
constexpr size_t OFF_YP    = OFF_CSP + 16384;         // [B,chunks,C,D]  4194304
constexpr size_t WS_NEED_PARTIAL = (OFF_YP + 4194304) * sizeof(float);
}  // namespace

// ---- k_xpart: column sums of x per 32-row chunk + fp16 copy. float4 loads.
__global__ __launch_bounds__(256) void k_xpart(const float* __restrict__ x,
                                               float* __restrict__ xpart,
                                               f16* __restrict__ xh) {
  const int b = blockIdx.x, j = blockIdx.y;
  const int t = threadIdx.x;
  const int rg = t >> 6, dq = t & 63;   // row-group (=wave), float4 column
  __shared__ float sL[4][kD];
  float4 s = {0.f, 0.f, 0.f, 0.f};
  const size_t rowbase = (size_t)b * kN + (size_t)j * 32;
#pragma unroll
  for (int i = 0; i < 8; ++i) {
    const int r = rg * 8 + i;
    const float4 q = *(reinterpret_cast<const float4*>(x + (rowbase + r) * kD) + dq);
    s.x += q.x; s.y += q.y; s.z += q.z; s.w += q.w;
    f16x4 h4 = {(f16)q.x, (f16)q.y, (f16)q.z, (f16)q.w};
    *(reinterpret_cast<f16x4*>(xh + (rowbase + r) * kD) + dq) = h4;
  }
  reinterpret_cast<float4*>(&sL[rg][0])[dq] = s;
  __syncthreads();
  const int d = t;
  xpart[((size_t)b * kXJ + j) * kD + d] =
      sL[0][d] + sL[1][d] + sL[2][d] + sL[3][d];
}

// ---- k_sv: s = y·W[c] + cs*b_caps[c]; v = squash(s); optional Wv (+)= W[c]·v (fp32+fp16)
__global__ __launch_bounds__(256) void k_sv(
    const float* __restrict__ W, const float* __restrict__ b_caps,
    const float* __restrict__ xpart, const float* __restrict__ y,
    const float* __restrict__ csum, const float* __restrict__ ypart,
    const float* __restrict__ cspart, float* __restrict__ v,
    float* __restrict__ Wv, f16* __restrict__ Wvh, float* __restrict__ bv,
    const int mode, const int computeWv, const int accWv, const int npart) {
  const int bc = blockIdx.x, b = bc >> 5, c = bc & 31;
  const int t = threadIdx.x;
  const int w = t >> 6, h = t & 63;
  __shared__ float yL[kD];
  __shared__ float sL[4][kH];
  __shared__ float vL[kH];
  __shared__ float csLs;

  if (mode == 0) {
    float s = 0.f;
#pragma unroll 8
    for (int j = 0; j < kXJ; ++j) s += xpart[((size_t)b * kXJ + j) * kD + t];
    yL[t] = s * (1.f / (float)kC);
    if (t == 0) csLs = (float)kN / (float)kC;
  } else if (npart > 0) {
    float s = 0.f;
#pragma unroll 8
    for (int ch = 0; ch < kChunks; ++ch)
      s += ypart[(((size_t)b * kChunks + ch) * kC + c) * kD + t];
    yL[t] = s;
    if (t < 32) {
      float cs_ = cspart[((size_t)b * kChunks + t) * kC + c];
#pragma unroll
      for (int off = 16; off; off >>= 1) cs_ += __shfl_xor(cs_, off, 64);
      if (t == 0) csLs = cs_;
    }
  } else {
    yL[t] = y[(size_t)bc * kD + t];
    if (t == 0) csLs = csum[bc];
  }
  __syncthreads();

  const float* Wc = W + (size_t)c * kD * kH;
  {
    float acc = 0.f;
#pragma unroll 8
    for (int d = w * 64; d < (w + 1) * 64; ++d)
      acc = fmaf(yL[d], Wc[(size_t)d * kH + h], acc);
    sL[w][h] = acc;
  }
  __syncthreads();

  if (t < 64) {
    const float bch = b_caps[c * kH + h];
    float s = sL[0][h] + sL[1][h] + sL[2][h] + sL[3][h] + csLs * bch;
    float s2 = s * s;
#pragma unroll
    for (int off = 32; off; off >>= 1) s2 += __shfl_xor(s2, off, 64);
    const float scale = s2 / (1.f + s2) * rsqrtf(s2 + 1e-7f);
    const float vh = scale * s;
    v[(size_t)bc * kH + h] = vh;
    vL[h] = vh;
    if (computeWv) {
      float bvp = bch * vh;
#pragma unroll
      for (int off = 32; off; off >>= 1) bvp += __shfl_xor(bvp, off, 64);
      if (h == 0) bv[bc] = accWv ? (bv[bc] + bvp) : bvp;
    }
  }
  __syncthreads();
  if (computeWv) {
    float acc = 0.f;
    const float* Wrow = Wc + (size_t)t * kH;
#pragma unroll 8
    for (int hh = 0; hh < kH; ++hh) acc = fmaf(Wrow[hh], vL[hh], acc);
    const size_t idx = (size_t)bc * kD + t;
    const float nv = accWv ? (Wv[idx] + acc) : acc;
    Wv[idx] = nv;
    Wvh[idx] = (f16)nv;
  }
}

// ---- k_route (MFMA): unchanged from round 8 (verified structure).
__global__ __launch_bounds__(256) void k_route(
    const f16* __restrict__ xh, const f16* __restrict__ Wvh,
    const float* __restrict__ bv, float* __restrict__ y,
    float* __restrict__ csum, float* __restrict__ ypart,
    float* __restrict__ cspart, const int usePart) {
  const int b = blockIdx.x, chunk = blockIdx.y;
  const int t = threadIdx.x;
  const int lane = t & 63, w = t >> 6;
  const int l15 = lane & 15, q = lane >> 4;

  __shared__ __align__(16) f16 xsT[kD][kRows + 8];
  __shared__ float aL[kRows][kC + 4];
  __shared__ __align__(16) f16 pT[kC][kRows + 8];
  __shared__ float csL[8][kC];

  const int n0 = chunk * kRows;
  const float bvc = bv[b * kC + (t & 31)];

  f32x4 acc0 = {0.f, 0.f, 0.f, 0.f}, acc1 = {0.f, 0.f, 0.f, 0.f};
  {
    const int row = w * 16 + l15;
    const f16x8* Ar = reinterpret_cast<const f16x8*>(
        xh + ((size_t)(b * kN + n0 + row)) * kD + q * 8);
    const f16x8* B0 = reinterpret_cast<const f16x8*>(
        Wvh + ((size_t)(b * kC + l15)) * kD + q * 8);
    const f16x8* B1 = reinterpret_cast<const f16x8*>(
        Wvh + ((size_t)(b * kC + 16 + l15)) * kD + q * 8);
#pragma unroll
    for (int ks = 0; ks < 8; ++ks) {
      f16x8 af = Ar[ks * 4];
      acc0 = __builtin_amdgcn_mfma_f32_16x16x32_f16(af, B0[ks * 4], acc0, 0, 0, 0);
      acc1 = __builtin_amdgcn_mfma_f32_16x16x32_f16(af, B1[ks * 4], acc1, 0, 0, 0);
      const int dbase = ks * 32 + q * 8;
#pragma unroll
      for (int i = 0; i < 8; ++i) {
        const int ii = (i + 2 * q) & 7;  // rotate: distinct banks across q-groups
        xsT[dbase + ii][row] = af[ii];
      }
    }
  }
#pragma unroll
  for (int r = 0; r < 4; ++r) {
    aL[w * 16 + q * 4 + r][l15] = acc0[r];
    aL[w * 16 + q * 4 + r][16 + l15] = acc1[r];
  }
  __syncthreads();

  const int c = t & 31, sg = t >> 5;
  float csreg = 0.f;
#pragma unroll
  for (int k = 0; k < 8; ++k) {
    const int r = sg * 8 + k;
    float L = bvc + aL[r][c];
    float m = L;
#pragma unroll
    for (int off = 16; off; off >>= 1) m = fmaxf(m, __shfl_xor(m, off, 64));
    const float e = __expf(L - m);
    float ssum = e;
#pragma unroll
    for (int off = 16; off; off >>= 1) ssum += __shfl_xor(ssum, off, 64);
    const float p = e / ssum;
    pT[c][r] = (f16)p;
    csreg += p;
  }
  csL[sg][c] = csreg;
  __syncthreads();

  const int mt2 = w & 1;
  const int ntb = (w >> 1) * 8;
  const f16x8 a0 = *reinterpret_cast<const f16x8*>(&pT[mt2 * 16 + l15][q * 8]);
  const f16x8 a1 = *reinterpret_cast<const f16x8*>(&pT[mt2 * 16 + l15][32 + q * 8]);
  const int cap = mt2 * 16 + q * 4;
#pragma unroll
  for (int i = 0; i < 8; ++i) {
    const int d0 = (ntb + i) * 16;
    const f16x8 b0 = *reinterpret_cast<const f16x8*>(&xsT[d0 + l15][q * 8]);
    const f16x8 b1 = *reinterpret_cast<const f16x8*>(&xsT[d0 + l15][32 + q * 8]);
    f32x4 o = {0.f, 0.f, 0.f, 0.f};
    o = __builtin_amdgcn_mfma_f32_16x16x32_f16(a0, b0, o, 0, 0, 0);
    o = __builtin_amdgcn_mfma_f32_16x16x32_f16(a1, b1, o, 0, 0, 0);
    if (usePart) {
      float* dst = ypart + (((size_t)(b * kChunks + chunk)) * kC + cap) * kD + d0 + l15;
#pragma unroll
      for (int r = 0; r < 4; ++r) dst[(size_t)r * kD] = o[r];
    } else {
      float* dst = y + ((size_t)(b * kC + cap)) * kD + d0 + l15;
#pragma unroll
      for (int r = 0; r < 4; ++r) atomicAdd(dst + (size_t)r * kD, o[r]);
    }
  }
  if (t < 32) {
    float s = 0.f;
#pragma unroll
    for (int j = 0; j < 8; ++j) s += csL[j][t];
    if (usePart) cspart[((size_t)b * kChunks + chunk) * kC + t] = s;
    else atomicAdd(csum + b * kC + t, s);
  }
}

// ---- k_tail: one block per b. ypart reduce -> GEMV+squash (v in LDS) ->
// per-head qkv/scores/softmax/ctx -> out-proj -> residual+LN+squash -> out.
__global__ __launch_bounds__(256) void k_tail(
    const float* __restrict__ W, const float* __restrict__ b_caps,
    const float* __restrict__ y, const float* __restrict__ csum,
    const float* __restrict__ ypart, const float* __restrict__ cspart,
    const float* __restrict__ Wq, const float* __restrict__ bq,
    const float* __restrict__ Wk, const float* __restrict__ bk,
    const float* __restrict__ Wvp, const float* __restrict__ bvp,
    const float* __restrict__ Wo, const float* __restrict__ bo,
    const float* __restrict__ ln_g, const float* __restrict__ ln_b,
    const float* __restrict__ gamma, float* __restrict__ out,
    const int usePart) {
  const int b = blockIdx.x, t = threadIdx.x;
  const int w = t >> 6, h = t & 63;
  __shared__ float yL[kC][kD];       // 32 KB; aliased as ctx[c][head*64+d] later
  __shared__ float rL[kC][kH];       // 8 KB (v = routed)
  __shared__ float csLs[kC];
  __shared__ float qLs[kC][kKD];
  __shared__ float kLs[kC][kKD + 1];
  __shared__ float vLs[kC][kKD];
  __shared__ float scs[kC][kC + 1];

  // ---- 1) reduce partials -> yL, csLs
  if (usePart) {
    const int c = t >> 3, fq = t & 7;   // 8 threads per capsule row
    float4 acc[8];
#pragma unroll
    for (int i = 0; i < 8; ++i) acc[i] = {0.f, 0.f, 0.f, 0.f};
    for (int ch = 0; ch < kChunks; ++ch) {
      const float4* src = reinterpret_cast<const float4*>(
          ypart + (((size_t)(b * kChunks + ch)) * kC + c) * kD);
#pragma unroll
      for (int i = 0; i < 8; ++i) {
        const float4 q = src[fq + 8 * i];
        acc[i].x += q.x; acc[i].y += q.y; acc[i].z += q.z; acc[i].w += q.w;
      }
    }
    float4* dst = reinterpret_cast<float4*>(&yL[c][0]);
#pragma unroll
    for (int i = 0; i < 8; ++i) dst[fq + 8 * i] = acc[i];
    if (t < kC) {
      float s = 0.f;
      for (int ch = 0; ch < kChunks; ++ch)
        s += cspart[((size_t)b * kChunks + ch) * kC + t];
      csLs[t] = s;
    }
  } else {
    const int c = t >> 3, fq = t & 7;
    const float4* src = reinterpret_cast<const float4*>(y + ((size_t)(b * kC + c)) * kD);
    float4* dst = reinterpret_cast<float4*>(&yL[c][0]);
#pragma unroll
    for (int i = 0; i < 8; ++i) dst[fq + 8 * i] = src[fq + 8 * i];
    if (t < kC) csLs[t] = csum[b * kC + t];
  }
  __syncthreads();

  // ---- 2) GEMV s[c][h] = yL[c]·W[c][:,h] + cs*b_caps; squash -> rL
  {
    float sacc[8];
#pragma unroll
    for (int i = 0; i < 8; ++i) {
      const int c = w + 4 * i;
      sacc[i] = csLs[c] * b_caps[c * kH + h];
    }
#pragma unroll
    for (int i = 0; i < 8; ++i) {
      const int c = w + 4 * i;
      const float* Wc = W + ((size_t)c * kD) * kH + h;
      float a = sacc[i];
#pragma unroll 8
      for (int d = 0; d < kD; ++d) a = fmaf(yL[c][d], Wc[(size_t)d * kH], a);
      sacc[i] = a;
    }
#pragma unroll
    for (int i = 0; i < 8; ++i) {
      const int c = w + 4 * i;
      float s2 = sacc[i] * sacc[i];
#pragma unroll
      for (int off = 32; off; off >>= 1) s2 += __shfl_xor(s2, off, 64);
      const float scale = s2 / (1.f + s2) * rsqrtf(s2 + 1e-7f);
      rL[c][h] = scale * sacc[i];
    }
  }
  __syncthreads();

  // ---- 3) per-head attention; ctx accumulates into yL alias
  for (int head = 0; head < kHeads; ++head) {
    float aq[8], ak[8], av[8];
    const float bq_ = bq[head * kKD + h];
    const float bk_ = bk[head * kKD + h];
    const float bv_ = bvp[head * kKD + h];
#pragma unroll
    for (int i = 0; i < 8; ++i) { aq[i] = bq_; ak[i] = bk_; av[i] = bv_; }
#pragma unroll 4
    for (int hh = 0; hh < kH; ++hh) {
      const size_t wi = ((size_t)hh * kHeads + head) * kKD + h;
      const float wq = Wq[wi], wk = Wk[wi], wv2 = Wvp[wi];
#pragma unroll
      for (int i = 0; i < 8; ++i) {
        const float r = rL[w + 4 * i][hh];
        aq[i] = fmaf(r, wq, aq[i]);
        ak[i] = fmaf(r, wk, ak[i]);
        av[i] = fmaf(r, wv2, av[i]);
      }
    }
#pragma unroll
    for (int i = 0; i < 8; ++i) {
      const int c = w + 4 * i;
      qLs[c][h] = aq[i]; kLs[c][h] = ak[i]; vLs[c][h] = av[i];
    }
    __syncthreads();
#pragma unroll
    for (int i2 = 0; i2 < 4; ++i2) {
      const int e = t + 256 * i2, qc = e >> 5, kc = e & 31;
      float s = 0.f;
#pragma unroll 8
      for (int d = 0; d < kKD; ++d) s = fmaf(qLs[qc][d], kLs[kc][d], s);
      scs[qc][kc] = s * 0.125f;
    }
    __syncthreads();
    if (t < kC) {
      float m = -1e30f;
#pragma unroll
      for (int kc = 0; kc < kC; ++kc) m = fmaxf(m, scs[t][kc]);
      float ssum = 0.f;
#pragma unroll
      for (int kc = 0; kc < kC; ++kc) {
        const float e2 = __expf(scs[t][kc] - m);
        scs[t][kc] = e2;
        ssum += e2;
      }
      const float inv = 1.f / ssum;
#pragma unroll
      for (int kc = 0; kc < kC; ++kc) scs[t][kc] *= inv;
    }
    __syncthreads();
#pragma unroll
    for (int i2 = 0; i2 < 8; ++i2) {
      const int e = t + 256 * i2, qc = e >> 6, d = e & 63;
      float s = 0.f;
#pragma unroll 8
      for (int kc = 0; kc < kC; ++kc) s = fmaf(scs[qc][kc], vLs[kc][d], s);
      yL[qc][head * kKD + d] = s;   // ctx alias (yL dead after GEMV)
    }
    __syncthreads();
  }

  // ---- 4) out-proj + residual + LN + squash*gamma
  {
    float accO[8];
    const float bo_ = bo[h];
#pragma unroll
    for (int i = 0; i < 8; ++i) accO[i] = bo_;
#pragma unroll 4
    for (int nd = 0; nd < kHeads * kKD; ++nd) {
      const float wo = Wo[(size_t)nd * kH + h];
#pragma unroll
      for (int i = 0; i < 8; ++i) accO[i] = fmaf(yL[w + 4 * i][nd], wo, accO[i]);
    }
    const float lg = ln_g[h], lb = ln_b[h], g0 = gamma[0];
#pragma unroll
    for (int i = 0; i < 8; ++i) {
      const int c = w + 4 * i;
      const float yv = accO[i] + rL[c][h];
      float mu = yv;
#pragma unroll
      for (int off = 32; off; off >>= 1) mu += __shfl_xor(mu, off, 64);
      mu *= (1.f / (float)kH);
      const float dv = yv - mu;
      float var = dv * dv;
#pragma unroll
      for (int off = 32; off; off >>= 1) var += __shfl_xor(var, off, 64);
      var *= (1.f / (float)kH);
      const float nrm = dv * rsqrtf(var + 1e-3f) * lg + lb;
      float s2 = nrm * nrm;
#pragma unroll
      for (int off = 32; off; off >>= 1) s2 += __shfl_xor(s2, off, 64);
      const float scale = s2 / (1.f + s2) * rsqrtf(s2 + 1e-7f);
      out[((size_t)b * kC + c) * kH + h] = scale * nrm * g0;
    }
  }
}

extern "C" void kernel_launch(void* const* d_in, const int* in_sizes, int n_in,
                              void* d_out, int out_size, void* d_ws, size_t ws_size,
                              hipStream_t stream) {
  (void)in_sizes; (void)n_in; (void)out_size;
  const float* x      = (const float*)d_in[0];
  const float* W      = (const float*)d_in[1];
  const float* b_caps = (const float*)d_in[2];
  const float* gamma  = (const float*)d_in[3];
  const float* Wq     = (const float*)d_in[4];
  const float* bq     = (const float*)d_in[5];
  const float* Wk     = (const float*)d_in[6];
  const float* bk     = (const float*)d_in[7];
  const float* Wv_in  = (const float*)d_in[8];
  const float* bv_in  = (const float*)d_in[9];
  const float* Wo     = (const float*)d_in[10];
  const float* bo     = (const float*)d_in[11];
  const float* ln_g   = (const float*)d_in[12];
  const float* ln_b   = (const float*)d_in[13];
  float* out = (float*)d_out;
  float* ws  = (float*)d_ws;

  float* xpart = ws + OFF_XPART;
  float* v     = ws + OFF_V;
  float* Wv    = ws + OFF_WV;
  float* bv    = ws + OFF_BV;
  float* y     = ws + OFF_Y;
  float* cs    = ws + OFF_CS;
  f16*   xf16  = (f16*)(ws + OFF_XF16);
  f16*   wvh   = (f16*)(ws + OFF_WVH);
  float* csp   = ws + OFF_CSP;
  float* yp    = ws + OFF_YP;

  const int usePart = (ws_size >= WS_NEED_PARTIAL) ? 1 : 0;

  k_xpart<<<dim3(kB, kXJ), 256, 0, stream>>>(x, xpart, xf16);
  k_sv<<<kB * kC, 256, 0, stream>>>(W, b_caps, xpart, y, cs, yp, csp, v, Wv, wvh, bv,
                                    /*mode=*/0, /*computeWv=*/1, /*accWv=*/0, 0);

  if (!usePart) {
    hipMemsetAsync(y, 0, (size_t)kB * kC * kD * sizeof(float), stream);
    hipMemsetAsync(cs, 0, (size_t)kB * kC * sizeof(float), stream);
  }
  k_route<<<dim3(kB, kChunks), 256, 0, stream>>>(xf16, wvh, bv, y, cs, yp, csp, usePart);
  k_sv<<<kB * kC, 256, 0, stream>>>(W, b_caps, xpart, y, cs, yp, csp, v, Wv, wvh, bv,
                                    /*mode=*/1, /*computeWv=*/1, /*accWv=*/1,
                                    usePart ? kChunks : 0);

  if (!usePart) {
    hipMemsetAsync(y, 0, (size_t)kB * kC * kD * sizeof(float), stream);
    hipMemsetAsync(cs, 0, (size_t)kB * kC * sizeof(float), stream);
  }
  k_route<<<dim3(kB, kChunks), 256, 0, stream>>>(xf16, wvh, bv, y, cs, yp, csp, usePart);

  k_tail<<<kB, 256, 0, stream>>>(W, b_caps, y, cs, yp, csp,
                                 Wq, bq, Wk, bk, Wv_in, bv_in, Wo, bo,
                                 ln_g, ln_b, gamma, out, usePart);
}

// Round 10
// 181.716 us; speedup vs baseline: 1.6978x; 1.6978x over previous
//
#include <hip/hip_runtime.h>
#include <cstddef>

typedef _Float16 f16;
typedef __attribute__((ext_vector_type(4))) _Float16 f16x4;
typedef __attribute__((ext_vector_type(8))) _Float16 f16x8;
typedef __attribute__((ext_vector_type(4))) float f32x4;

namespace {
constexpr int kB = 16;
constexpr int kN = 2048;
constexpr int kD = 256;   // D_IN
constexpr int kC = 32;
constexpr int kH = 64;
constexpr int kHeads = 4;
constexpr int kKD = 64;
constexpr int kChunks = 32;                  // route n-chunks per b
constexpr int kRows = kN / kChunks;          // 64 rows per chunk
constexpr int kXJ = 64;                      // xpart sub-chunks (32 rows each)

// workspace offsets (floats)
constexpr size_t OFF_XPART = 0;                       // [B,64,D]         262144
constexpr size_t OFF_V     = OFF_XPART + 262144;      // [B,C,H]           32768
constexpr size_t OFF_WV    = OFF_V + 32768;           // [B,C,D] fp32     131072
constexpr size_t OFF_BV    = OFF_WV + 131072;         // [B,C]               512
constexpr size_t OFF_Y     = OFF_BV + 512;            // [B,C,D] (atomic) 131072
constexpr size_t OFF_CS    = OFF_Y + 131072;          // [B,C]               512
constexpr size_t OFF_QKV   = OFF_CS + 512;            // [3,B,H,C,KD]     393216
constexpr size_t OFF_CTX   = OFF_QKV + 393216;        // [B,C,HEADS,KD]   524288
constexpr size_t OFF_XF16  = OFF_CTX + 524288;        // [B,N,D] f16     4194304
constexpr size_t OFF_WVH   = OFF_XF16 + 4194304;      // [B,C,D] f16       65536
constexpr size_t OFF_CSP   = OFF_WVH + 65536;         // [B,chunks,C]      16384
constexpr size_t OFF_YP    = OFF_CSP + 16384;         // [B,chunks,C,D]  4194304
constexpr size_t WS_NEED_PARTIAL = (OFF_YP + 4194304) * sizeof(float);
}  // namespace

// ---- k_xpart: column sums of x per 32-row chunk + fp16 copy. float4 loads.
__global__ __launch_bounds__(256) void k_xpart(const float* __restrict__ x,
                                               float* __restrict__ xpart,
                                               f16* __restrict__ xh) {
  const int b = blockIdx.x, j = blockIdx.y;
  const int t = threadIdx.x;
  const int rg = t >> 6, dq = t & 63;   // row-group (=wave), float4 column
  __shared__ float sL[4][kD];
  float4 s = {0.f, 0.f, 0.f, 0.f};
  const size_t rowbase = (size_t)b * kN + (size_t)j * 32;
#pragma unroll
  for (int i = 0; i < 8; ++i) {
    const int r = rg * 8 + i;
    const float4 q = *(reinterpret_cast<const float4*>(x + (rowbase + r) * kD) + dq);
    s.x += q.x; s.y += q.y; s.z += q.z; s.w += q.w;
    f16x4 h4 = {(f16)q.x, (f16)q.y, (f16)q.z, (f16)q.w};
    *(reinterpret_cast<f16x4*>(xh + (rowbase + r) * kD) + dq) = h4;
  }
  reinterpret_cast<float4*>(&sL[rg][0])[dq] = s;
  __syncthreads();
  const int d = t;
  xpart[((size_t)b * kXJ + j) * kD + d] =
      sL[0][d] + sL[1][d] + sL[2][d] + sL[3][d];
}

// ---- k_sv: s = y·W[c] + cs*b_caps[c]; v = squash(s); optional Wv (+)= W[c]·v (fp32+fp16)
__global__ __launch_bounds__(256) void k_sv(
    const float* __restrict__ W, const float* __restrict__ b_caps,
    const float* __restrict__ xpart, const float* __restrict__ y,
    const float* __restrict__ csum, const float* __restrict__ ypart,
    const float* __restrict__ cspart, float* __restrict__ v,
    float* __restrict__ Wv, f16* __restrict__ Wvh, float* __restrict__ bv,
    const int mode, const int computeWv, const int accWv, const int npart) {
  const int bc = blockIdx.x, b = bc >> 5, c = bc & 31;
  const int t = threadIdx.x;
  const int w = t >> 6, h = t & 63;
  __shared__ float yL[kD];
  __shared__ float sL[4][kH];
  __shared__ float vL[kH];
  __shared__ float csLs;

  if (mode == 0) {
    float s = 0.f;
#pragma unroll 8
    for (int j = 0; j < kXJ; ++j) s += xpart[((size_t)b * kXJ + j) * kD + t];
    yL[t] = s * (1.f / (float)kC);
    if (t == 0) csLs = (float)kN / (float)kC;
  } else if (npart > 0) {
    float s = 0.f;
#pragma unroll 8
    for (int ch = 0; ch < kChunks; ++ch)
      s += ypart[(((size_t)b * kChunks + ch) * kC + c) * kD + t];
    yL[t] = s;
    if (t < 32) {
      float cs_ = cspart[((size_t)b * kChunks + t) * kC + c];
#pragma unroll
      for (int off = 16; off; off >>= 1) cs_ += __shfl_xor(cs_, off, 64);
      if (t == 0) csLs = cs_;
    }
  } else {
    yL[t] = y[(size_t)bc * kD + t];
    if (t == 0) csLs = csum[bc];
  }
  __syncthreads();

  const float* Wc = W + (size_t)c * kD * kH;
  {
    float acc = 0.f;
#pragma unroll 8
    for (int d = w * 64; d < (w + 1) * 64; ++d)
      acc = fmaf(yL[d], Wc[(size_t)d * kH + h], acc);
    sL[w][h] = acc;
  }
  __syncthreads();

  if (t < 64) {
    const float bch = b_caps[c * kH + h];
    float s = sL[0][h] + sL[1][h] + sL[2][h] + sL[3][h] + csLs * bch;
    float s2 = s * s;
#pragma unroll
    for (int off = 32; off; off >>= 1) s2 += __shfl_xor(s2, off, 64);
    const float scale = s2 / (1.f + s2) * rsqrtf(s2 + 1e-7f);
    const float vh = scale * s;
    v[(size_t)bc * kH + h] = vh;
    vL[h] = vh;
    if (computeWv) {
      float bvp = bch * vh;
#pragma unroll
      for (int off = 32; off; off >>= 1) bvp += __shfl_xor(bvp, off, 64);
      if (h == 0) bv[bc] = accWv ? (bv[bc] + bvp) : bvp;
    }
  }
  __syncthreads();
  if (computeWv) {
    float acc = 0.f;
    const float* Wrow = Wc + (size_t)t * kH;
#pragma unroll 8
    for (int hh = 0; hh < kH; ++hh) acc = fmaf(Wrow[hh], vL[hh], acc);
    const size_t idx = (size_t)bc * kD + t;
    const float nv = accWv ? (Wv[idx] + acc) : acc;
    Wv[idx] = nv;
    Wvh[idx] = (f16)nv;
  }
}

// ---- k_route (MFMA): round-8 verified structure.
__global__ __launch_bounds__(256) void k_route(
    const f16* __restrict__ xh, const f16* __restrict__ Wvh,
    const float* __restrict__ bv, float* __restrict__ y,
    float* __restrict__ csum, float* __restrict__ ypart,
    float* __restrict__ cspart, const int usePart) {
  const int b = blockIdx.x, chunk = blockIdx.y;
  const int t = threadIdx.x;
  const int lane = t & 63, w = t >> 6;
  const int l15 = lane & 15, q = lane >> 4;

  __shared__ __align__(16) f16 xsT[kD][kRows + 8];
  __shared__ float aL[kRows][kC + 4];
  __shared__ __align__(16) f16 pT[kC][kRows + 8];
  __shared__ float csL[8][kC];

  const int n0 = chunk * kRows;
  const float bvc = bv[b * kC + (t & 31)];

  f32x4 acc0 = {0.f, 0.f, 0.f, 0.f}, acc1 = {0.f, 0.f, 0.f, 0.f};
  {
    const int row = w * 16 + l15;
    const f16x8* Ar = reinterpret_cast<const f16x8*>(
        xh + ((size_t)(b * kN + n0 + row)) * kD + q * 8);
    const f16x8* B0 = reinterpret_cast<const f16x8*>(
        Wvh + ((size_t)(b * kC + l15)) * kD + q * 8);
    const f16x8* B1 = reinterpret_cast<const f16x8*>(
        Wvh + ((size_t)(b * kC + 16 + l15)) * kD + q * 8);
#pragma unroll
    for (int ks = 0; ks < 8; ++ks) {
      f16x8 af = Ar[ks * 4];
      acc0 = __builtin_amdgcn_mfma_f32_16x16x32_f16(af, B0[ks * 4], acc0, 0, 0, 0);
      acc1 = __builtin_amdgcn_mfma_f32_16x16x32_f16(af, B1[ks * 4], acc1, 0, 0, 0);
      const int dbase = ks * 32 + q * 8;
#pragma unroll
      for (int i = 0; i < 8; ++i) {
        const int ii = (i + 2 * q) & 7;  // rotate: distinct banks across q-groups
        xsT[dbase + ii][row] = af[ii];
      }
    }
  }
#pragma unroll
  for (int r = 0; r < 4; ++r) {
    aL[w * 16 + q * 4 + r][l15] = acc0[r];
    aL[w * 16 + q * 4 + r][16 + l15] = acc1[r];
  }
  __syncthreads();

  const int c = t & 31, sg = t >> 5;
  float csreg = 0.f;
#pragma unroll
  for (int k = 0; k < 8; ++k) {
    const int r = sg * 8 + k;
    float L = bvc + aL[r][c];
    float m = L;
#pragma unroll
    for (int off = 16; off; off >>= 1) m = fmaxf(m, __shfl_xor(m, off, 64));
    const float e = __expf(L - m);
    float ssum = e;
#pragma unroll
    for (int off = 16; off; off >>= 1) ssum += __shfl_xor(ssum, off, 64);
    const float p = e / ssum;
    pT[c][r] = (f16)p;
    csreg += p;
  }
  csL[sg][c] = csreg;
  __syncthreads();

  const int mt2 = w & 1;
  const int ntb = (w >> 1) * 8;
  const f16x8 a0 = *reinterpret_cast<const f16x8*>(&pT[mt2 * 16 + l15][q * 8]);
  const f16x8 a1 = *reinterpret_cast<const f16x8*>(&pT[mt2 * 16 + l15][32 + q * 8]);
  const int cap = mt2 * 16 + q * 4;
#pragma unroll
  for (int i = 0; i < 8; ++i) {
    const int d0 = (ntb + i) * 16;
    const f16x8 b0 = *reinterpret_cast<const f16x8*>(&xsT[d0 + l15][q * 8]);
    const f16x8 b1 = *reinterpret_cast<const f16x8*>(&xsT[d0 + l15][32 + q * 8]);
    f32x4 o = {0.f, 0.f, 0.f, 0.f};
    o = __builtin_amdgcn_mfma_f32_16x16x32_f16(a0, b0, o, 0, 0, 0);
    o = __builtin_amdgcn_mfma_f32_16x16x32_f16(a1, b1, o, 0, 0, 0);
    if (usePart) {
      float* dst = ypart + (((size_t)(b * kChunks + chunk)) * kC + cap) * kD + d0 + l15;
#pragma unroll
      for (int r = 0; r < 4; ++r) dst[(size_t)r * kD] = o[r];
    } else {
      float* dst = y + ((size_t)(b * kC + cap)) * kD + d0 + l15;
#pragma unroll
      for (int r = 0; r < 4; ++r) atomicAdd(dst + (size_t)r * kD, o[r]);
    }
  }
  if (t < 32) {
    float s = 0.f;
#pragma unroll
    for (int j = 0; j < 8; ++j) s += csL[j][t];
    if (usePart) cspart[((size_t)b * kChunks + chunk) * kC + t] = s;
    else atomicAdd(csum + b * kC + t, s);
  }
}

// ---- k_qkv: one projection per block, grid (B, HEADS, 3).
__global__ __launch_bounds__(256) void k_qkv(
    const float* __restrict__ routed, const float* __restrict__ Wq,
    const float* __restrict__ bq, const float* __restrict__ Wk,
    const float* __restrict__ bk, const float* __restrict__ Wvp,
    const float* __restrict__ bvp, float* __restrict__ qkv) {
  const int b = blockIdx.x, head = blockIdx.y, which = blockIdx.z;
  const int t = threadIdx.x;
  const int kk = t & 63, w = t >> 6;
  const float* Wsrc = (which == 0) ? Wq : (which == 1) ? Wk : Wvp;
  const float* bsrc = (which == 0) ? bq : (which == 1) ? bk : bvp;
  __shared__ float rL[kC * kH];
#pragma unroll
  for (int i = 0; i < 8; ++i) rL[t + 256 * i] = routed[(size_t)b * kC * kH + t + 256 * i];
  __syncthreads();
  float acc[8];
  const float bb = bsrc[head * kKD + kk];
#pragma unroll
  for (int i = 0; i < 8; ++i) acc[i] = bb;
#pragma unroll 4
  for (int hh = 0; hh < kH; ++hh) {
    const float wv = Wsrc[((size_t)hh * kHeads + head) * kKD + kk];
#pragma unroll
    for (int i = 0; i < 8; ++i)
      acc[i] = fmaf(rL[(w + 4 * i) * kH + hh], wv, acc[i]);
  }
#pragma unroll
  for (int i = 0; i < 8; ++i) {
    const int cc = w + 4 * i;
    qkv[((((size_t)which * kB + b) * kHeads + head) * kC + cc) * kKD + kk] = acc[i];
  }
}

// ---- k_attn2: scores + softmax + ctx from staged q/k/v. grid (B, HEADS).
__global__ __launch_bounds__(256) void k_attn2(const float* __restrict__ qkv,
                                               float* __restrict__ ctx) {
  const int b = blockIdx.x, head = blockIdx.y, t = threadIdx.x;
  constexpr size_t kWhichStride = (size_t)kB * kHeads * kC * kKD;
  const size_t base = ((size_t)b * kHeads + head) * kC * kKD;
  __shared__ float qL[kC][kKD];
  __shared__ float kL[kC][kKD + 1];
  __shared__ float vL[kC][kKD];
  __shared__ float sc[kC][kC + 1];
#pragma unroll
  for (int i = 0; i < 8; ++i) {
    const int e = t + 256 * i, cc = e >> 6, kk = e & 63;
    qL[cc][kk] = qkv[base + e];
    kL[cc][kk] = qkv[base + kWhichStride + e];
    vL[cc][kk] = qkv[base + 2 * kWhichStride + e];
  }
  __syncthreads();
#pragma unroll
  for (int i = 0; i < 4; ++i) {
    const int e = t + 256 * i, qc = e >> 5, kc = e & 31;
    float s = 0.f;
#pragma unroll 8
    for (int d = 0; d < kKD; ++d) s = fmaf(qL[qc][d], kL[kc][d], s);
    sc[qc][kc] = s * 0.125f;
  }
  __syncthreads();
  if (t < kC) {
    float m = -1e30f;
#pragma unroll
    for (int kc = 0; kc < kC; ++kc) m = fmaxf(m, sc[t][kc]);
    float ssum = 0.f;
#pragma unroll
    for (int kc = 0; kc < kC; ++kc) {
      const float e2 = __expf(sc[t][kc] - m);
      sc[t][kc] = e2;
      ssum += e2;
    }
    const float inv = 1.f / ssum;
#pragma unroll
    for (int kc = 0; kc < kC; ++kc) sc[t][kc] *= inv;
  }
  __syncthreads();
#pragma unroll
  for (int i = 0; i < 8; ++i) {
    const int e = t + 256 * i, qc = e >> 6, d = e & 63;
    float s = 0.f;
#pragma unroll 8
    for (int kc = 0; kc < kC; ++kc) s = fmaf(sc[qc][kc], vL[kc][d], s);
    ctx[(((size_t)b * kC + qc) * kHeads + head) * kKD + d] = s;
  }
}

// ---- k_final: out-proj + residual + LN + squash*gamma. Block = (b,c).
__global__ __launch_bounds__(256) void k_final(
    const float* __restrict__ ctx, const float* __restrict__ Wo,
    const float* __restrict__ bo, const float* __restrict__ routed,
    const float* __restrict__ ln_g, const float* __restrict__ ln_b,
    const float* __restrict__ gamma, float* __restrict__ out) {
  const int bc = blockIdx.x, t = threadIdx.x;
  const int w = t >> 6, h = t & 63;
  __shared__ float cL[kHeads * kKD];
  __shared__ float sL[4][kH];
  cL[t] = ctx[(size_t)bc * (kHeads * kKD) + t];
  __syncthreads();
  float acc = 0.f;
#pragma unroll 8
  for (int nd = w * 64; nd < (w + 1) * 64; ++nd)
    acc = fmaf(cL[nd], Wo[(size_t)nd * kH + h], acc);
  sL[w][h] = acc;
  __syncthreads();
  if (t < 64) {
    const float yv = sL[0][h] + sL[1][h] + sL[2][h] + sL[3][h] + bo[h] +
                     routed[(size_t)bc * kH + h];
    float mu = yv;
#pragma unroll
    for (int off = 32; off; off >>= 1) mu += __shfl_xor(mu, off, 64);
    mu *= (1.f / (float)kH);
    const float dv = yv - mu;
    float var = dv * dv;
#pragma unroll
    for (int off = 32; off; off >>= 1) var += __shfl_xor(var, off, 64);
    var *= (1.f / (float)kH);
    const float nrm = dv * rsqrtf(var + 1e-3f) * ln_g[h] + ln_b[h];
    float s2 = nrm * nrm;
#pragma unroll
    for (int off = 32; off; off >>= 1) s2 += __shfl_xor(s2, off, 64);
    const float scale = s2 / (1.f + s2) * rsqrtf(s2 + 1e-7f);
    out[(size_t)bc * kH + h] = scale * nrm * gamma[0];
  }
}

extern "C" void kernel_launch(void* const* d_in, const int* in_sizes, int n_in,
                              void* d_out, int out_size, void* d_ws, size_t ws_size,
                              hipStream_t stream) {
  (void)in_sizes; (void)n_in; (void)out_size;
  const float* x      = (const float*)d_in[0];
  const float* W      = (const float*)d_in[1];
  const float* b_caps = (const float*)d_in[2];
  const float* gamma  = (const float*)d_in[3];
  const float* Wq     = (const float*)d_in[4];
  const float* bq     = (const float*)d_in[5];
  const float* Wk     = (const float*)d_in[6];
  const float* bk     = (const float*)d_in[7];
  const float* Wv_in  = (const float*)d_in[8];
  const float* bv_in  = (const float*)d_in[9];
  const float* Wo     = (const float*)d_in[10];
  const float* bo     = (const float*)d_in[11];
  const float* ln_g   = (const float*)d_in[12];
  const float* ln_b   = (const float*)d_in[13];
  float* out = (float*)d_out;
  float* ws  = (float*)d_ws;

  float* xpart = ws + OFF_XPART;
  float* v     = ws + OFF_V;
  float* Wv    = ws + OFF_WV;
  float* bv    = ws + OFF_BV;
  float* y     = ws + OFF_Y;
  float* cs    = ws + OFF_CS;
  float* qkv   = ws + OFF_QKV;
  float* ctx   = ws + OFF_CTX;
  f16*   xf16  = (f16*)(ws + OFF_XF16);
  f16*   wvh   = (f16*)(ws + OFF_WVH);
  float* csp   = ws + OFF_CSP;
  float* yp    = ws + OFF_YP;

  const int usePart = (ws_size >= WS_NEED_PARTIAL) ? 1 : 0;

  k_xpart<<<dim3(kB, kXJ), 256, 0, stream>>>(x, xpart, xf16);
  k_sv<<<kB * kC, 256, 0, stream>>>(W, b_caps, xpart, y, cs, yp, csp, v, Wv, wvh, bv,
                                    /*mode=*/0, /*computeWv=*/1, /*accWv=*/0, 0);

  if (!usePart) {
    hipMemsetAsync(y, 0, (size_t)kB * kC * kD * sizeof(float), stream);
    hipMemsetAsync(cs, 0, (size_t)kB * kC * sizeof(float), stream);
  }
  k_route<<<dim3(kB, kChunks), 256, 0, stream>>>(xf16, wvh, bv, y, cs, yp, csp, usePart);
  k_sv<<<kB * kC, 256, 0, stream>>>(W, b_caps, xpart, y, cs, yp, csp, v, Wv, wvh, bv,
                                    /*mode=*/1, /*computeWv=*/1, /*accWv=*/1,
                                    usePart ? kChunks : 0);

  if (!usePart) {
    hipMemsetAsync(y, 0, (size_t)kB * kC * kD * sizeof(float), stream);
    hipMemsetAsync(cs, 0, (size_t)kB * kC * sizeof(float), stream);
  }
  k_route<<<dim3(kB, kChunks), 256, 0, stream>>>(xf16, wvh, bv, y, cs, yp, csp, usePart);
  k_sv<<<kB * kC, 256, 0, stream>>>(W, b_caps, xpart, y, cs, yp, csp, v, Wv, wvh, bv,
                                    /*mode=*/1, /*computeWv=*/0, /*accWv=*/0,
                                    usePart ? kChunks : 0);

  k_qkv<<<dim3(kB, kHeads, 3), 256, 0, stream>>>(v, Wq, bq, Wk, bk, Wv_in, bv_in, qkv);
  k_attn2<<<dim3(kB, kHeads), 256, 0, stream>>>(qkv, ctx);
  k_final<<<kB * kC, 256, 0, stream>>>(ctx, Wo, bo, v, ln_g, ln_b, gamma, out);
}